// Round 1
// baseline (676.871 us; speedup 1.0000x reference)
//
#include <hip/hip_runtime.h>

#define DEV __device__ __forceinline__

typedef __bf16 bf16;
typedef bf16 bf16x4 __attribute__((ext_vector_type(4)));
typedef bf16 bf16x8 __attribute__((ext_vector_type(8)));
typedef float f32x4 __attribute__((ext_vector_type(4)));

constexpr int N_NODES = 16384;
constexpr int KN = 25;               // neighbors per node
constexpr int DS = 256, DN = 256, DL = 64;

// ws layout (bytes)
constexpr size_t WS_WLT  = 0;                  // bf16 W_linkT [256][64]   = 32768 B
constexpr size_t WS_WCAT = 32768;              // bf16 WT_cat  [512][256]  = 262144 B
constexpr size_t WS_EXP  = 32768 + 262144;     // bf16 expected [16384][256] = 8 MB

DEV float sigmoid_fast(float x) {
    return __builtin_amdgcn_rcpf(1.0f + __builtin_amdgcn_exp2f(-1.44269504088896341f * x));
}

DEV float dot4(f32x4 a, f32x4 b) {
    return a[0] * b[0] + a[1] * b[1] + a[2] * b[2] + a[3] * b[3];
}

// ---------------------------------------------------------------------------
// Kernel 0: convert + transpose weights to bf16 in ws
// ---------------------------------------------------------------------------
__global__ void prep_kernel(const float* __restrict__ W_link,
                            const float* __restrict__ W_self,
                            const float* __restrict__ W_neigh,
                            bf16* __restrict__ wlT, bf16* __restrict__ wcat) {
    int tid = blockIdx.x * blockDim.x + threadIdx.x;
    int stride = gridDim.x * blockDim.x;
    for (int i = tid; i < DL * DN; i += stride) {
        int d = i >> 6, l = i & 63;
        wlT[i] = (bf16)W_link[l * DN + d];         // W_linkT[d][l]
    }
    for (int i = tid; i < 512 * 256; i += stride) {
        int j = i >> 8, kk = i & 255;
        float v = (j < 256) ? W_self[kk * 256 + j] : W_neigh[kk * 256 + (j - 256)];
        wcat[i] = (bf16)v;
    }
}

// ---------------------------------------------------------------------------
// Kernel A: per-WAVE fused gate + link-MFMA + amplify + weighted mean.
// No barriers in the node loop; each neigh row read exactly once.
// T14 issue-early: per half, all neigh-row loads are issued BEFORE the
// MFMA/sigmoid phase and held in registers, so ~900cy HBM latency hides
// under ~1300cy of MFMA + transcendental work instead of stalling the k-loop.
// ---------------------------------------------------------------------------
constexpr int NPW = 8;     // nodes per wave; grid = 16384/(4*NPW) = 512 blocks
constexpr int WTS = 72;    // WT row stride (elems): 144 B, breaks b128 conflicts
constexpr int STS = 264;   // ST row stride (elems): 528 B

__global__ __launch_bounds__(256, 2)
void fused_agg_kernel(const float* __restrict__ self_vecs,
                      const float* __restrict__ neigh_vecs,
                      const float* __restrict__ link_vecs,
                      const float* __restrict__ probs,
                      const float* __restrict__ g_self_w,
                      const float* __restrict__ g_neigh_w,
                      const float* __restrict__ g_link_w,
                      const bf16* __restrict__ wlT,
                      bf16* __restrict__ exp_out) {
    __shared__ bf16 WT[256 * WTS];        // 36 KB, shared: W_linkT [d][l]
    __shared__ bf16 ST[4][16 * STS];      // 33 KB: per-wave sigmoid(trans_links) 16 rows

    const int tid = threadIdx.x;
    const int lane = tid & 63;
    const int w = tid >> 6;
    const int c = lane & 15;
    const int q = lane >> 4;

    // stage W_linkT -> LDS once
    for (int i = 0; i < 16; ++i) {
        int idx = i * 1024 + tid * 4;
        int d = idx >> 6, l = idx & 63;
        *(bf16x4*)&WT[d * WTS + l] = *(const bf16x4*)&wlT[idx];
    }
    __syncthreads();

    // per-lane weight preloads
    f32x4 gsw = *(const f32x4*)&g_self_w[lane * 4];
    f32x4 gnw = *(const f32x4*)&g_neigh_w[lane * 4];
    f32x4 glw0a = *(const f32x4*)&g_link_w[q * 8];
    f32x4 glw0b = *(const f32x4*)&g_link_w[q * 8 + 4];
    f32x4 glw1a = *(const f32x4*)&g_link_w[32 + q * 8];
    f32x4 glw1b = *(const f32x4*)&g_link_w[32 + q * 8 + 4];

    for (int it = 0; it < NPW; ++it) {
        const int n = (blockIdx.x * 4 + w) * NPW + it;
        const float* nbase = neigh_vecs + (size_t)n * KN * DN;
        const float* lbase = link_vecs + (size_t)n * KN * DL;

        // ---- trans_self (full-wave dot) ----
        f32x4 sv = *(const f32x4*)&self_vecs[(size_t)n * DS + lane * 4];
        float ts = dot4(sv, gsw);
#pragma unroll
        for (int off = 1; off < 64; off <<= 1) ts += __shfl_xor(ts, off);

        // ---- link fragments (MFMA-A layout, straight from global) + trans_link ----
        // frag A: rows 0..15 (row = c); frag B: rows 16..31 (row = c+16, pad>=25 zero)
        f32x4 v0 = *(const f32x4*)&lbase[c * DL + q * 8];
        f32x4 v1 = *(const f32x4*)&lbase[c * DL + q * 8 + 4];
        f32x4 v2 = *(const f32x4*)&lbase[c * DL + 32 + q * 8];
        f32x4 v3 = *(const f32x4*)&lbase[c * DL + 32 + q * 8 + 4];
        const int rB = c + 16;
        const f32x4 z = {0.f, 0.f, 0.f, 0.f};
        f32x4 u0 = z, u1 = z, u2 = z, u3 = z;
        if (rB < KN) {
            u0 = *(const f32x4*)&lbase[rB * DL + q * 8];
            u1 = *(const f32x4*)&lbase[rB * DL + q * 8 + 4];
            u2 = *(const f32x4*)&lbase[rB * DL + 32 + q * 8];
            u3 = *(const f32x4*)&lbase[rB * DL + 32 + q * 8 + 4];
        }
        bf16x8 a00, a01, a10, a11;
#pragma unroll
        for (int j = 0; j < 4; ++j) {
            a00[j] = (bf16)v0[j]; a00[j + 4] = (bf16)v1[j];
            a01[j] = (bf16)v2[j]; a01[j + 4] = (bf16)v3[j];
            a10[j] = (bf16)u0[j]; a10[j + 4] = (bf16)u1[j];
            a11[j] = (bf16)u2[j]; a11[j + 4] = (bf16)u3[j];
        }
        float tlA = dot4(v0, glw0a) + dot4(v1, glw0b) + dot4(v2, glw1a) + dot4(v3, glw1b);
        tlA += __shfl_xor(tlA, 16); tlA += __shfl_xor(tlA, 32);
        float tlB = dot4(u0, glw0a) + dot4(u1, glw0b) + dot4(u2, glw1a) + dot4(u3, glw1b);
        tlB += __shfl_xor(tlB, 16); tlB += __shfl_xor(tlB, 32);

        // lane k (k=0..24) holds gate partial ts+tl[k] and 1/(p[k]*25)
        float gk = ts + ((lane & 63) < 16 ? tlA : tlB);
        float pv = (lane < KN) ? probs[n * KN + lane] : 1.0f;
        float wden = __builtin_amdgcn_rcpf(pv * 25.0f);

        f32x4 accd = z;    // expected accumulator: cols lane*4..+3

#pragma unroll
        for (int half = 0; half < 2; ++half) {
            const bf16x8 aF0 = half ? a10 : a00;
            const bf16x8 aF1 = half ? a11 : a01;
            const int k0 = half * 16;
            const int kcnt = half ? (KN - 16) : 16;   // 16 or 9

            // ---- T14 issue-early: prefetch this half's neigh rows into regs.
            // Loads are in flight while the MFMA+sigmoid phase below runs
            // (vmcnt only waited at first use in the k-loop).
            f32x4 nv[16];
#pragma unroll
            for (int kk = 0; kk < 16; ++kk) {
                if (kk < kcnt)
                    nv[kk] = *(const f32x4*)&nbase[(size_t)(k0 + kk) * DN + lane * 4];
            }

            // MFMA 16 rows x 256 cols, sigmoid, stash bf16 to per-wave LDS
#pragma unroll
            for (int t = 0; t < 16; ++t) {
                bf16x8 b0 = *(const bf16x8*)&WT[(t * 16 + c) * WTS + q * 8];
                bf16x8 b1 = *(const bf16x8*)&WT[(t * 16 + c) * WTS + 32 + q * 8];
                f32x4 acc = z;
                acc = __builtin_amdgcn_mfma_f32_16x16x32_bf16(aF0, b0, acc, 0, 0, 0);
                acc = __builtin_amdgcn_mfma_f32_16x16x32_bf16(aF1, b1, acc, 0, 0, 0);
#pragma unroll
                for (int r = 0; r < 4; ++r)
                    ST[w][(q * 4 + r) * STS + t * 16 + c] = (bf16)sigmoid_fast(acc[r]);
            }

            // single pass over this half's neigh rows (registers, no vm stall)
#pragma unroll
            for (int kk = 0; kk < kcnt; ++kk) {
                const int k = k0 + kk;
                f32x4 nvk = nv[kk];
                bf16x4 s4 = *(const bf16x4*)&ST[w][kk * STS + lane * 4];
                float tn = dot4(nvk, gnw);
#pragma unroll
                for (int off = 1; off < 64; off <<= 1) tn += __shfl_xor(tn, off);
                float wkk = sigmoid_fast(tn + __shfl(gk, k)) * __shfl(wden, k);
#pragma unroll
                for (int j = 0; j < 4; ++j)
                    accd[j] += nvk[j] * (float)s4[j] * wkk;
            }
        }

        bf16x4 eo;
#pragma unroll
        for (int j = 0; j < 4; ++j) eo[j] = (bf16)accd[j];
        *(bf16x4*)&exp_out[(size_t)n * DN + lane * 4] = eo;
    }
}

// ---------------------------------------------------------------------------
// Kernel B: out = relu([self | expected] @ blockdiag(W_self, W_neigh))
// ---------------------------------------------------------------------------
constexpr int BPAD = 72;

__global__ __launch_bounds__(256, 2)
void out_gemm_kernel(const float* __restrict__ self_vecs,
                     const bf16* __restrict__ exp_in,
                     const bf16* __restrict__ wcat,
                     float* __restrict__ out) {
    __shared__ bf16 As[64 * BPAD];
    __shared__ bf16 Bs[64 * BPAD];
    const int tid = threadIdx.x;
    const int lane = tid & 63;
    const int w = tid >> 6;
    const int c = lane & 15, q = lane >> 4;
    const int wm = w >> 1, wn = w & 1;
    const int m0 = blockIdx.x * 64;
    const int j0 = blockIdx.y * 64;
    const bool use_exp = j0 >= 256;

    f32x4 acc[2][2];
#pragma unroll
    for (int i = 0; i < 2; ++i)
#pragma unroll
        for (int j = 0; j < 2; ++j) acc[i][j] = (f32x4){0.f, 0.f, 0.f, 0.f};

    const int srow = tid >> 4;
    const int scol = (tid & 15) * 4;

    for (int ks = 0; ks < 4; ++ks) {
        const int k0 = ks * 64;
        __syncthreads();
#pragma unroll
        for (int i = 0; i < 4; ++i) {
            int row = srow + i * 16;
            if (use_exp) {
                *(bf16x4*)&As[row * BPAD + scol] =
                    *(const bf16x4*)&exp_in[(size_t)(m0 + row) * 256 + k0 + scol];
            } else {
                f32x4 v = *(const f32x4*)&self_vecs[(size_t)(m0 + row) * 256 + k0 + scol];
                bf16x4 b; b[0] = (bf16)v[0]; b[1] = (bf16)v[1]; b[2] = (bf16)v[2]; b[3] = (bf16)v[3];
                *(bf16x4*)&As[row * BPAD + scol] = b;
            }
            *(bf16x4*)&Bs[row * BPAD + scol] =
                *(const bf16x4*)&wcat[(size_t)(j0 + row) * 256 + k0 + scol];
        }
        __syncthreads();
        const int kc = q * 8;
#pragma unroll
        for (int i = 0; i < 2; ++i) {
            bf16x8 a0 = *(const bf16x8*)&As[(wm * 32 + i * 16 + c) * BPAD + kc];
            bf16x8 a1 = *(const bf16x8*)&As[(wm * 32 + i * 16 + c) * BPAD + kc + 32];
#pragma unroll
            for (int j = 0; j < 2; ++j) {
                bf16x8 b0 = *(const bf16x8*)&Bs[(wn * 32 + j * 16 + c) * BPAD + kc];
                bf16x8 b1 = *(const bf16x8*)&Bs[(wn * 32 + j * 16 + c) * BPAD + kc + 32];
                acc[i][j] = __builtin_amdgcn_mfma_f32_16x16x32_bf16(a0, b0, acc[i][j], 0, 0, 0);
                acc[i][j] = __builtin_amdgcn_mfma_f32_16x16x32_bf16(a1, b1, acc[i][j], 0, 0, 0);
            }
        }
    }

#pragma unroll
    for (int i = 0; i < 2; ++i)
#pragma unroll
        for (int j = 0; j < 2; ++j)
#pragma unroll
            for (int r = 0; r < 4; ++r) {
                int row = m0 + wm * 32 + i * 16 + q * 4 + r;
                int col = j0 + wn * 32 + j * 16 + c;
                float v = acc[i][j][r];
                out[(size_t)row * 512 + col] = v > 0.f ? v : 0.f;
            }
}

// ---------------------------------------------------------------------------
extern "C" void kernel_launch(void* const* d_in, const int* in_sizes, int n_in,
                              void* d_out, int out_size, void* d_ws, size_t ws_size,
                              hipStream_t stream) {
    const float* self_vecs  = (const float*)d_in[0];
    const float* neigh_vecs = (const float*)d_in[1];
    const float* link_vecs  = (const float*)d_in[2];
    const float* probs      = (const float*)d_in[3];
    const float* g_self_w   = (const float*)d_in[4];
    const float* g_neigh_w  = (const float*)d_in[5];
    const float* g_link_w   = (const float*)d_in[6];
    const float* W_link     = (const float*)d_in[7];
    const float* W_self     = (const float*)d_in[8];
    const float* W_neigh    = (const float*)d_in[9];
    float* out = (float*)d_out;

    char* ws = (char*)d_ws;
    bf16* wlT  = (bf16*)(ws + WS_WLT);
    bf16* wcat = (bf16*)(ws + WS_WCAT);
    bf16* expb = (bf16*)(ws + WS_EXP);

    prep_kernel<<<dim3(128), dim3(256), 0, stream>>>(W_link, W_self, W_neigh, wlT, wcat);
    fused_agg_kernel<<<dim3(N_NODES / (4 * NPW)), dim3(256), 0, stream>>>(
        self_vecs, neigh_vecs, link_vecs, probs, g_self_w, g_neigh_w, g_link_w, wlT, expb);
    out_gemm_kernel<<<dim3(256, 8), dim3(256), 0, stream>>>(self_vecs, expb, wcat, out);
}

// Round 2
// 675.354 us; speedup vs baseline: 1.0022x; 1.0022x over previous
//
#include <hip/hip_runtime.h>

#define DEV __device__ __forceinline__

typedef __bf16 bf16;
typedef bf16 bf16x4 __attribute__((ext_vector_type(4)));
typedef bf16 bf16x8 __attribute__((ext_vector_type(8)));
typedef float f32x4 __attribute__((ext_vector_type(4)));

constexpr int N_NODES = 16384;
constexpr int KN = 25;               // neighbors per node
constexpr int DS = 256, DN = 256, DL = 64;

// ws layout (bytes)
constexpr size_t WS_WLT  = 0;                  // bf16 W_linkT [256][64]   = 32768 B
constexpr size_t WS_WCAT = 32768;              // bf16 WT_cat  [512][256]  = 262144 B
constexpr size_t WS_EXP  = 32768 + 262144;     // bf16 expected [16384][256] = 8 MB

DEV float sigmoid_fast(float x) {
    return __builtin_amdgcn_rcpf(1.0f + __builtin_amdgcn_exp2f(-1.44269504088896341f * x));
}

DEV float dot4(f32x4 a, f32x4 b) {
    return a[0] * b[0] + a[1] * b[1] + a[2] * b[2] + a[3] * b[3];
}

// ---------------------------------------------------------------------------
// Kernel 0: convert + transpose weights to bf16 in ws
// ---------------------------------------------------------------------------
__global__ void prep_kernel(const float* __restrict__ W_link,
                            const float* __restrict__ W_self,
                            const float* __restrict__ W_neigh,
                            bf16* __restrict__ wlT, bf16* __restrict__ wcat) {
    int tid = blockIdx.x * blockDim.x + threadIdx.x;
    int stride = gridDim.x * blockDim.x;
    for (int i = tid; i < DL * DN; i += stride) {
        int d = i >> 6, l = i & 63;
        wlT[i] = (bf16)W_link[l * DN + d];         // W_linkT[d][l]
    }
    for (int i = tid; i < 512 * 256; i += stride) {
        int j = i >> 8, kk = i & 255;
        float v = (j < 256) ? W_self[kk * 256 + j] : W_neigh[kk * 256 + (j - 256)];
        wcat[i] = (bf16)v;
    }
}

// ---------------------------------------------------------------------------
// Kernel A: per-WAVE fused gate + link-MFMA + amplify + weighted mean.
// No barriers in the node loop; each neigh row read exactly once.
// Pipelining:
//  - neigh rows for each half prefetched to regs before the MFMA phase (T14)
//  - link/self/probs for node it+1 reissued into the SAME loop-carried regs
//    immediately after their last use for node it, so the node-head gate
//    phase never eats a cold ~900cy HBM stall.
// ---------------------------------------------------------------------------
constexpr int NPW = 8;     // nodes per wave; grid = 16384/(4*NPW) = 512 blocks
constexpr int WTS = 72;    // WT row stride (elems): 144 B, breaks b128 conflicts
constexpr int STS = 264;   // ST row stride (elems): 528 B

__global__ __launch_bounds__(256, 2)
void fused_agg_kernel(const float* __restrict__ self_vecs,
                      const float* __restrict__ neigh_vecs,
                      const float* __restrict__ link_vecs,
                      const float* __restrict__ probs,
                      const float* __restrict__ g_self_w,
                      const float* __restrict__ g_neigh_w,
                      const float* __restrict__ g_link_w,
                      const bf16* __restrict__ wlT,
                      bf16* __restrict__ exp_out) {
    __shared__ bf16 WT[256 * WTS];        // 36 KB, shared: W_linkT [d][l]
    __shared__ bf16 ST[4][16 * STS];      // 33 KB: per-wave sigmoid(trans_links) 16 rows

    const int tid = threadIdx.x;
    const int lane = tid & 63;
    const int w = tid >> 6;
    const int c = lane & 15;
    const int q = lane >> 4;

    // stage W_linkT -> LDS once
    for (int i = 0; i < 16; ++i) {
        int idx = i * 1024 + tid * 4;
        int d = idx >> 6, l = idx & 63;
        *(bf16x4*)&WT[d * WTS + l] = *(const bf16x4*)&wlT[idx];
    }
    __syncthreads();

    // per-lane weight preloads
    f32x4 gsw = *(const f32x4*)&g_self_w[lane * 4];
    f32x4 gnw = *(const f32x4*)&g_neigh_w[lane * 4];
    f32x4 glw0a = *(const f32x4*)&g_link_w[q * 8];
    f32x4 glw0b = *(const f32x4*)&g_link_w[q * 8 + 4];
    f32x4 glw1a = *(const f32x4*)&g_link_w[32 + q * 8];
    f32x4 glw1b = *(const f32x4*)&g_link_w[32 + q * 8 + 4];

    const int rB = c + 16;
    const f32x4 z = {0.f, 0.f, 0.f, 0.f};
    const int nfirst = (blockIdx.x * 4 + w) * NPW;

    // ---- loop-carried node-head registers (link frags / self / probs) ----
    f32x4 sv, v0, v1, v2, v3, u0, u1, u2, u3;
    float pvr;
    {
        const float* lb = link_vecs + (size_t)nfirst * KN * DL;
        sv = *(const f32x4*)&self_vecs[(size_t)nfirst * DS + lane * 4];
        v0 = *(const f32x4*)&lb[c * DL + q * 8];
        v1 = *(const f32x4*)&lb[c * DL + q * 8 + 4];
        v2 = *(const f32x4*)&lb[c * DL + 32 + q * 8];
        v3 = *(const f32x4*)&lb[c * DL + 32 + q * 8 + 4];
        u0 = z; u1 = z; u2 = z; u3 = z;
        if (rB < KN) {
            u0 = *(const f32x4*)&lb[rB * DL + q * 8];
            u1 = *(const f32x4*)&lb[rB * DL + q * 8 + 4];
            u2 = *(const f32x4*)&lb[rB * DL + 32 + q * 8];
            u3 = *(const f32x4*)&lb[rB * DL + 32 + q * 8 + 4];
        }
        pvr = (lane < KN) ? probs[(size_t)nfirst * KN + lane] : 1.0f;
    }

    for (int it = 0; it < NPW; ++it) {
        const int n = nfirst + it;
        const float* nbase = neigh_vecs + (size_t)n * KN * DN;

        // ---- consume node-head regs: trans_self, fragments, trans_link ----
        float ts = dot4(sv, gsw);
#pragma unroll
        for (int off = 1; off < 64; off <<= 1) ts += __shfl_xor(ts, off);

        bf16x8 a00, a01, a10, a11;
#pragma unroll
        for (int j = 0; j < 4; ++j) {
            a00[j] = (bf16)v0[j]; a00[j + 4] = (bf16)v1[j];
            a01[j] = (bf16)v2[j]; a01[j + 4] = (bf16)v3[j];
            a10[j] = (bf16)u0[j]; a10[j + 4] = (bf16)u1[j];
            a11[j] = (bf16)u2[j]; a11[j + 4] = (bf16)u3[j];
        }
        float tlA = dot4(v0, glw0a) + dot4(v1, glw0b) + dot4(v2, glw1a) + dot4(v3, glw1b);
        tlA += __shfl_xor(tlA, 16); tlA += __shfl_xor(tlA, 32);
        float tlB = dot4(u0, glw0a) + dot4(u1, glw0b) + dot4(u2, glw1a) + dot4(u3, glw1b);
        tlB += __shfl_xor(tlB, 16); tlB += __shfl_xor(tlB, 32);

        float gk = ts + (lane < 16 ? tlA : tlB);
        float wden = __builtin_amdgcn_rcpf(pvr * 25.0f);

        // ---- reissue node-head loads for it+1 (in flight across halves) ----
        if (it + 1 < NPW) {
            const int n2 = n + 1;
            const float* lb2 = link_vecs + (size_t)n2 * KN * DL;
            sv = *(const f32x4*)&self_vecs[(size_t)n2 * DS + lane * 4];
            v0 = *(const f32x4*)&lb2[c * DL + q * 8];
            v1 = *(const f32x4*)&lb2[c * DL + q * 8 + 4];
            v2 = *(const f32x4*)&lb2[c * DL + 32 + q * 8];
            v3 = *(const f32x4*)&lb2[c * DL + 32 + q * 8 + 4];
            u0 = z; u1 = z; u2 = z; u3 = z;
            if (rB < KN) {
                u0 = *(const f32x4*)&lb2[rB * DL + q * 8];
                u1 = *(const f32x4*)&lb2[rB * DL + q * 8 + 4];
                u2 = *(const f32x4*)&lb2[rB * DL + 32 + q * 8];
                u3 = *(const f32x4*)&lb2[rB * DL + 32 + q * 8 + 4];
            }
            pvr = (lane < KN) ? probs[(size_t)n2 * KN + lane] : 1.0f;
        }

        f32x4 accd = z;    // expected accumulator: cols lane*4..+3

#pragma unroll
        for (int half = 0; half < 2; ++half) {
            const bf16x8 aF0 = half ? a10 : a00;
            const bf16x8 aF1 = half ? a11 : a01;
            const int k0 = half * 16;
            const int kcnt = half ? (KN - 16) : 16;   // 16 or 9

            // T14 issue-early: this half's neigh rows into regs; loads fly
            // under the MFMA+sigmoid phase below.
            f32x4 nv[16];
#pragma unroll
            for (int kk = 0; kk < 16; ++kk) {
                if (kk < kcnt)
                    nv[kk] = *(const f32x4*)&nbase[(size_t)(k0 + kk) * DN + lane * 4];
            }

            // MFMA 16 rows x 256 cols, sigmoid, stash bf16 to per-wave LDS
#pragma unroll
            for (int t = 0; t < 16; ++t) {
                bf16x8 b0 = *(const bf16x8*)&WT[(t * 16 + c) * WTS + q * 8];
                bf16x8 b1 = *(const bf16x8*)&WT[(t * 16 + c) * WTS + 32 + q * 8];
                f32x4 acc = z;
                acc = __builtin_amdgcn_mfma_f32_16x16x32_bf16(aF0, b0, acc, 0, 0, 0);
                acc = __builtin_amdgcn_mfma_f32_16x16x32_bf16(aF1, b1, acc, 0, 0, 0);
#pragma unroll
                for (int r = 0; r < 4; ++r)
                    ST[w][(q * 4 + r) * STS + t * 16 + c] = (bf16)sigmoid_fast(acc[r]);
            }

            // single pass over this half's neigh rows (registers, no vm stall)
#pragma unroll
            for (int kk = 0; kk < kcnt; ++kk) {
                const int k = k0 + kk;
                f32x4 nvk = nv[kk];
                bf16x4 s4 = *(const bf16x4*)&ST[w][kk * STS + lane * 4];
                float tn = dot4(nvk, gnw);
#pragma unroll
                for (int off = 1; off < 64; off <<= 1) tn += __shfl_xor(tn, off);
                float wkk = sigmoid_fast(tn + __shfl(gk, k)) * __shfl(wden, k);
#pragma unroll
                for (int j = 0; j < 4; ++j)
                    accd[j] += nvk[j] * (float)s4[j] * wkk;
            }
        }

        bf16x4 eo;
#pragma unroll
        for (int j = 0; j < 4; ++j) eo[j] = (bf16)accd[j];
        *(bf16x4*)&exp_out[(size_t)n * DN + lane * 4] = eo;
    }
}

// ---------------------------------------------------------------------------
// Kernel B: out = relu([self | expected] @ blockdiag(W_self, W_neigh))
// Merged-y: each block does 64 rows x 256 output cols, so self/exp A-tiles
// are fetched from HBM exactly once (was 4x across y-blocks).
// ---------------------------------------------------------------------------
constexpr int BPAD = 72;

__global__ __launch_bounds__(256, 2)
void out_gemm_kernel(const float* __restrict__ self_vecs,
                     const bf16* __restrict__ exp_in,
                     const bf16* __restrict__ wcat,
                     float* __restrict__ out) {
    __shared__ bf16 As[64 * BPAD];        // 9 KB
    __shared__ bf16 Bs[256 * BPAD];       // 36 KB
    const int tid = threadIdx.x;
    const int lane = tid & 63;
    const int w = tid >> 6;
    const int c = lane & 15, q = lane >> 4;
    const int wm = w >> 1;                 // 32-row half
    const int wn = w & 1;                  // 128-col half
    const int m0 = blockIdx.x * 64;
    const int jbase = blockIdx.y * 256;    // 0 = self-cols, 256 = neigh-cols
    const bool use_exp = blockIdx.y != 0;

    f32x4 acc[2][8];
#pragma unroll
    for (int i = 0; i < 2; ++i)
#pragma unroll
        for (int j = 0; j < 8; ++j) acc[i][j] = (f32x4){0.f, 0.f, 0.f, 0.f};

    const int srow = tid >> 4;
    const int scol = (tid & 15) * 4;

    for (int ks = 0; ks < 4; ++ks) {
        const int k0 = ks * 64;
        __syncthreads();
        // A-tile: 64 rows x 64 k
#pragma unroll
        for (int i = 0; i < 4; ++i) {
            int row = srow + i * 16;
            if (use_exp) {
                *(bf16x4*)&As[row * BPAD + scol] =
                    *(const bf16x4*)&exp_in[(size_t)(m0 + row) * 256 + k0 + scol];
            } else {
                f32x4 v = *(const f32x4*)&self_vecs[(size_t)(m0 + row) * 256 + k0 + scol];
                bf16x4 b; b[0] = (bf16)v[0]; b[1] = (bf16)v[1]; b[2] = (bf16)v[2]; b[3] = (bf16)v[3];
                *(bf16x4*)&As[row * BPAD + scol] = b;
            }
        }
        // B-tile: 256 wcat rows (output cols) x 64 k
#pragma unroll
        for (int i = 0; i < 16; ++i) {
            int row = srow + i * 16;
            *(bf16x4*)&Bs[row * BPAD + scol] =
                *(const bf16x4*)&wcat[(size_t)(jbase + row) * 256 + k0 + scol];
        }
        __syncthreads();
        const int kc = q * 8;
#pragma unroll
        for (int i = 0; i < 2; ++i) {
            bf16x8 a0 = *(const bf16x8*)&As[(wm * 32 + i * 16 + c) * BPAD + kc];
            bf16x8 a1 = *(const bf16x8*)&As[(wm * 32 + i * 16 + c) * BPAD + kc + 32];
#pragma unroll
            for (int j = 0; j < 8; ++j) {
                bf16x8 b0 = *(const bf16x8*)&Bs[(wn * 128 + j * 16 + c) * BPAD + kc];
                bf16x8 b1 = *(const bf16x8*)&Bs[(wn * 128 + j * 16 + c) * BPAD + kc + 32];
                acc[i][j] = __builtin_amdgcn_mfma_f32_16x16x32_bf16(a0, b0, acc[i][j], 0, 0, 0);
                acc[i][j] = __builtin_amdgcn_mfma_f32_16x16x32_bf16(a1, b1, acc[i][j], 0, 0, 0);
            }
        }
    }

#pragma unroll
    for (int i = 0; i < 2; ++i)
#pragma unroll
        for (int j = 0; j < 8; ++j)
#pragma unroll
            for (int r = 0; r < 4; ++r) {
                int row = m0 + wm * 32 + i * 16 + q * 4 + r;
                int col = jbase + wn * 128 + j * 16 + c;
                float v = acc[i][j][r];
                out[(size_t)row * 512 + col] = v > 0.f ? v : 0.f;
            }
}

// ---------------------------------------------------------------------------
extern "C" void kernel_launch(void* const* d_in, const int* in_sizes, int n_in,
                              void* d_out, int out_size, void* d_ws, size_t ws_size,
                              hipStream_t stream) {
    const float* self_vecs  = (const float*)d_in[0];
    const float* neigh_vecs = (const float*)d_in[1];
    const float* link_vecs  = (const float*)d_in[2];
    const float* probs      = (const float*)d_in[3];
    const float* g_self_w   = (const float*)d_in[4];
    const float* g_neigh_w  = (const float*)d_in[5];
    const float* g_link_w   = (const float*)d_in[6];
    const float* W_link     = (const float*)d_in[7];
    const float* W_self     = (const float*)d_in[8];
    const float* W_neigh    = (const float*)d_in[9];
    float* out = (float*)d_out;

    char* ws = (char*)d_ws;
    bf16* wlT  = (bf16*)(ws + WS_WLT);
    bf16* wcat = (bf16*)(ws + WS_WCAT);
    bf16* expb = (bf16*)(ws + WS_EXP);

    prep_kernel<<<dim3(128), dim3(256), 0, stream>>>(W_link, W_self, W_neigh, wlT, wcat);
    fused_agg_kernel<<<dim3(N_NODES / (4 * NPW)), dim3(256), 0, stream>>>(
        self_vecs, neigh_vecs, link_vecs, probs, g_self_w, g_neigh_w, g_link_w, wlT, expb);
    out_gemm_kernel<<<dim3(256, 2), dim3(256), 0, stream>>>(self_vecs, expb, wcat, out);
}